// Round 9
// baseline (203.230 us; speedup 1.0000x reference)
//
#include <hip/hip_runtime.h>
#include <hip/hip_bf16.h>

// TFData2VecVisionSelfAttention: B=16,S=577,D=768,H=12,HEAD=64. fp32 in/out.
// R18: qkv_gemm restored to the R10 8-phase 256x256 template (measured 55.3us,
// MfmaUtil 22.5, 0 conflicts) -- the R11 256x384 2-phase rewrite was actually
// ~75us all along; a flaky rocprof top-5 join hid it and I mis-inferred
// "<55us" from its absence. Only change vs R10: QSCALE/log2e folding so the
// exp2f attn path (R17) stays correct. prep/prep2/attn = R17 byte-identical.
// Workspace (bytes, phase-overlapped), total 67.1 MB:
//   qkv   [0, 42541056)                      3 x 9232x768 bf16 m-major (q,k,v)
//   WT    [42541056, 46080000)   phase 1     3x768x768 bf16
//   Xb    [46080000, 60260352)   phase 1     9232x768 bf16
//   vT    [42541056, 58269696)   phase 2     192x64x640 bf16 (over WT+Xb)
//   biasm [58269696, 67132416)   phase 2     12x577x640 bf16 (over Xb tail)

typedef __attribute__((ext_vector_type(8))) short bf16x8;   // 8 x bf16 (4 VGPRs)
typedef __attribute__((ext_vector_type(4))) float f32x4;
typedef unsigned short u16;

#define SEQ 577
#define MTOT 9232            // 16*577
#define QKV_STRIDE 7090176   // 9232*768 elements per q/k/v buffer
#define VT_PITCH 640         // keys per vT row (pad 577..639 zero-filled)
#define B_PITCH 640          // bias row pitch (pad = bf16(-144))
#define QSCALE 0.18033688f   // 0.125 * log2(e)
#define LOG2E 1.44269504f

// fp32 -> bf16 round-to-nearest-even
static __device__ __forceinline__ u16 f2bf(float x) {
  unsigned int u = __float_as_uint(x);
  u = (u + 0x7FFFu + ((u >> 16) & 1u)) >> 16;
  return (u16)u;
}
static __device__ __forceinline__ float bf2f(u16 v) {
  return __uint_as_float(((unsigned int)v) << 16);
}

// async global->LDS, 16B per lane; LDS dest = wave-uniform base + lane*16
static __device__ __forceinline__ void gload_lds16(const void* g, void* l) {
  __builtin_amdgcn_global_load_lds(
      (const __attribute__((address_space(1))) unsigned int*)g,
      (__attribute__((address_space(3))) unsigned int*)l, 16, 0, 0);
}

// ---------------- prep: transpose_w (blocks 0..1727) + cvt_x (1728..5189) ----------------
__global__ __launch_bounds__(256) void prep(
    const float* __restrict__ Wq, const float* __restrict__ Wk,
    const float* __restrict__ Wv, const float* __restrict__ X,
    u16* __restrict__ WT, u16* __restrict__ Xb) {
  const int bid = blockIdx.x;
  if (bid < 1728) {
    __shared__ float t[32][33];
    const int z = bid / 576;
    const int rem = bid - z * 576;
    const int kx = rem % 24, ny = rem / 24;
    const float* W = (z == 0) ? Wq : (z == 1) ? Wk : Wv;
    int x = threadIdx.x & 31;
    int y = threadIdx.x >> 5;  // 0..7
    int k0 = kx * 32;
    int n0 = ny * 32;
#pragma unroll
    for (int i = 0; i < 4; ++i)
      t[y + i * 8][x] = W[(size_t)(k0 + y + i * 8) * 768 + n0 + x];
    __syncthreads();
    u16* o = WT + (size_t)z * 589824;
#pragma unroll
    for (int i = 0; i < 4; ++i)
      o[(size_t)(n0 + y + i * 8) * 768 + k0 + x] = f2bf(t[x][y + i * 8]);
  } else {
    size_t i = ((size_t)(bid - 1728) * 256 + threadIdx.x) * 8;
    if (i >= (size_t)MTOT * 768) return;
    const float4* xp = (const float4*)(X + i);
    float4 a = xp[0], b = xp[1];
    u16 pk[8] = {f2bf(a.x), f2bf(a.y), f2bf(a.z), f2bf(a.w),
                 f2bf(b.x), f2bf(b.y), f2bf(b.z), f2bf(b.w)};
    *(int4*)(Xb + i) = *(const int4*)pk;
  }
}

// ---------------- prep2: transpose_v (blocks 0..959) + bias_pre (960..1536) ----------------
__global__ __launch_bounds__(256) void prep2(
    const u16* __restrict__ v,      // v buffer, [m][768]
    u16* __restrict__ vT,           // [bh][64][640]
    const float* __restrict__ table, const int* __restrict__ idx,
    u16* __restrict__ biasm) {
  const int bid = blockIdx.x;
  const int tid = threadIdx.x;
  if (bid < 960) {
    const int tile = bid % 5;   // s0 = tile*128
    const int bh = bid / 5;     // 0..191
    const int b = bh / 12, h = bh % 12;
    __shared__ u16 T[128][64];
    const int s0 = tile * 128;
    const u16* vp = v + (size_t)b * SEQ * 768 + h * 64;
#pragma unroll
    for (int it = 0; it < 4; ++it) {
      int c = tid + it * 256;          // 1024 chunks of 16B
      int r = c >> 3, ko = (c & 7) << 3;
      int gs = s0 + r;
      int4 val = make_int4(0, 0, 0, 0);
      if (gs < SEQ) val = *(const int4*)(vp + (size_t)gs * 768 + ko);
      *(int4*)&T[r][ko ^ (((r >> 3) & 7) << 3)] = val;  // swizzled store
    }
    __syncthreads();
    u16* op = vT + (size_t)bh * 64 * VT_PITCH;
#pragma unroll
    for (int it = 0; it < 4; ++it) {
      int c = tid + it * 256;          // d = c>>4, so = (c&15)*8
      int d = c >> 4, so = (c & 15) << 3;
      u16 tmp[8];
#pragma unroll
      for (int j = 0; j < 8; ++j) {
        int rr = so + j;
        tmp[j] = T[rr][d ^ (((rr >> 3) & 7) << 3)];
      }
      *(int4*)(op + (size_t)d * VT_PITCH + s0 + so) = *(const int4*)tmp;
    }
  } else {
    // bias gather, h-vectorized: one block per q-row. idx read once per
    // (q,k); table row (12 floats = 48B) via 3x float4; values pre-scaled
    // by log2e for attn's exp2. 12 coalesced u16 plane-stores.
    const int q = bid - 960;        // 0..576
    const int* idxq = idx + q * SEQ;
    const u16 pad = f2bf(-144.0f);
    for (int k = tid; k < B_PITCH; k += 256) {
      u16 vv[12];
      if (k < SEQ) {
        const float4* tp = (const float4*)(table + (size_t)idxq[k] * 12);
        float4 t0 = tp[0], t1 = tp[1], t2 = tp[2];
        vv[0] = f2bf(t0.x * LOG2E);  vv[1] = f2bf(t0.y * LOG2E);
        vv[2] = f2bf(t0.z * LOG2E);  vv[3] = f2bf(t0.w * LOG2E);
        vv[4] = f2bf(t1.x * LOG2E);  vv[5] = f2bf(t1.y * LOG2E);
        vv[6] = f2bf(t1.z * LOG2E);  vv[7] = f2bf(t1.w * LOG2E);
        vv[8] = f2bf(t2.x * LOG2E);  vv[9] = f2bf(t2.y * LOG2E);
        vv[10] = f2bf(t2.z * LOG2E); vv[11] = f2bf(t2.w * LOG2E);
      } else {
#pragma unroll
        for (int h = 0; h < 12; ++h) vv[h] = pad;  // pad keys self-mask
      }
#pragma unroll
      for (int h = 0; h < 12; ++h)
        biasm[((size_t)h * SEQ + q) * B_PITCH + k] = vv[h];
    }
  }
}

// ---------------- fused QKV GEMM: 256x256 tile, BK=64, 8 waves, 8-phase ----------------
// R10 template (measured 55.3us): grid 37 M-tiles x 9 N-tiles, mt pinned to
// XCD. LDS TILES[2 dbuf][A,B][256][64] = 128 KiB, st-16-style XOR swizzle
// (linear gload_lds dest + inverse-swizzled global src + swizzled ds_read).
// 4 phases per K-tile {ds_read quadrant | stage 1 half-tile -> barrier ->
// lgkmcnt(0) -> setprio(1) -> 16 MFMA -> setprio(0) -> barrier}; counted
// s_waitcnt vmcnt(6) only at K-tile boundaries (3 half-tiles in flight).
#define STAGE_A(BUF, KT, MH)                                                   \
  do {                                                                         \
    gload_lds16(asrc[(MH)] + (KT) * 64, &TILES[(BUF)][0][(MH) * 64 + w8][0]);  \
    gload_lds16(asrc[(MH) + 2] + (KT) * 64,                                    \
                &TILES[(BUF)][0][128 + (MH) * 64 + w8][0]);                    \
  } while (0)

#define STAGE_B(BUF, KT, NH)                                                   \
  do {                                                                         \
    gload_lds16(bsrc + (size_t)((NH) * 32) * 768 + (KT) * 64,                  \
                &TILES[(BUF)][1][bw + (NH) * 32][0]);                          \
    gload_lds16(bsrc + (size_t)(128 + (NH) * 32) * 768 + (KT) * 64,            \
                &TILES[(BUF)][1][128 + bw + (NH) * 32][0]);                    \
  } while (0)

#define LOAD_A(BUF, MH)                                                        \
  do {                                                                         \
    const char* _p =                                                           \
        (const char*)&TILES[(BUF)][0][wm2 * 128 + (MH) * 64 + l15][0];         \
    af[0][0] = *(const bf16x8*)(_p + ca0);                                     \
    af[0][1] = *(const bf16x8*)(_p + ca1);                                     \
    af[1][0] = *(const bf16x8*)(_p + 2048 + ca0);                              \
    af[1][1] = *(const bf16x8*)(_p + 2048 + ca1);                              \
    af[2][0] = *(const bf16x8*)(_p + 4096 + ca0);                              \
    af[2][1] = *(const bf16x8*)(_p + 4096 + ca1);                              \
    af[3][0] = *(const bf16x8*)(_p + 6144 + ca0);                              \
    af[3][1] = *(const bf16x8*)(_p + 6144 + ca1);                              \
  } while (0)

#define LOAD_B(BUF, NH)                                                        \
  do {                                                                         \
    const char* _p =                                                           \
        (const char*)&TILES[(BUF)][1][wn * 64 + (NH) * 32 + l15][0];           \
    bfr[0][0] = *(const bf16x8*)(_p + ca0);                                    \
    bfr[0][1] = *(const bf16x8*)(_p + ca1);                                    \
    bfr[1][0] = *(const bf16x8*)(_p + 2048 + ca0);                             \
    bfr[1][1] = *(const bf16x8*)(_p + 2048 + ca1);                             \
  } while (0)

#define MFMA_Q(MH, NH)                                                         \
  do {                                                                         \
    _Pragma("unroll") for (int _i = 0; _i < 4; ++_i)                           \
        _Pragma("unroll") for (int _j = 0; _j < 2; ++_j)                       \
            acc[(MH) * 4 + _i][(NH) * 2 + _j] =                                \
        __builtin_amdgcn_mfma_f32_16x16x32_bf16(                               \
            af[_i][0], bfr[_j][0], acc[(MH) * 4 + _i][(NH) * 2 + _j], 0, 0,    \
            0);                                                                \
    _Pragma("unroll") for (int _i = 0; _i < 4; ++_i)                           \
        _Pragma("unroll") for (int _j = 0; _j < 2; ++_j)                       \
            acc[(MH) * 4 + _i][(NH) * 2 + _j] =                                \
        __builtin_amdgcn_mfma_f32_16x16x32_bf16(                               \
            af[_i][1], bfr[_j][1], acc[(MH) * 4 + _i][(NH) * 2 + _j], 0, 0,    \
            0);                                                                \
  } while (0)

#define PH_MID                                                                 \
  do {                                                                         \
    asm volatile("" ::: "memory");                                             \
    __builtin_amdgcn_s_barrier();                                              \
    asm volatile("s_waitcnt lgkmcnt(0)" ::: "memory");                         \
    __builtin_amdgcn_s_setprio(1);                                             \
  } while (0)

#define PH_END                                                                 \
  do {                                                                         \
    __builtin_amdgcn_s_setprio(0);                                             \
    asm volatile("" ::: "memory");                                             \
    __builtin_amdgcn_s_barrier();                                              \
    asm volatile("" ::: "memory");                                             \
  } while (0)

__global__ __launch_bounds__(512, 2) void qkv_gemm(
    const u16* __restrict__ Xb,   // [9232][768] bf16
    const u16* __restrict__ WT,   // [3][768][768] n-major bf16
    const float* __restrict__ bq, const float* __restrict__ bv,
    u16* __restrict__ qkv) {
  const int bid = blockIdx.x;
  const int xcd = bid & 7;
  const int r8 = bid >> 3;                 // 0..44
  const int mt = (r8 / 9) * 8 + xcd;       // all 9 nt of one mt -> same XCD
  if (mt >= 37) return;
  const int nt = r8 % 9;
  const int m0 = mt * 256;
  const int widx = nt / 3;                 // 0=q, 1=k, 2=v
  const int nb = (nt % 3) * 256;           // col base within [0,768)

  const int tid = threadIdx.x;
  const int lane = tid & 63;
  const int w = tid >> 6;                  // 0..7
  const int wm2 = w >> 2;                  // 0..1 (M half)
  const int wn = w & 3;                    // 0..3 (N quarter)
  const int quad = lane >> 4;
  const int l15 = lane & 15;

  __shared__ u16 TILES[2][2][256][64];     // 128 KiB

  // ---- staging addressing (per-lane swizzled global src, per-wave LDS base)
  const int lr = lane >> 3;                // row within an 8-row group
  const int w8 = w * 8;
  const int ce = ((lane & 7) ^ lr) * 8;    // swizzled src element offset
  const u16* asrc[4];                      // A chunk row bases 0/64/128/192
#pragma unroll
  for (int c = 0; c < 4; ++c) {
    int rr = m0 + c * 64 + w8 + lr;
    if (rr > MTOT - 1) rr = MTOT - 1;      // clamped rows: garbage, not stored
    asrc[c] = Xb + (size_t)rr * 768 + ce;
  }
  const int bw = (w >> 2) * 64 + (w & 3) * 8;
  const u16* bsrc = WT + (size_t)widx * 589824 + (size_t)(nb + bw + lr) * 768 + ce;

  // ---- ds_read addressing (swizzled) ----
  const int lswz = (l15 & 7) << 4;
  const int ca0 = (quad * 16) ^ lswz;      // k-half 0
  const int ca1 = ca0 ^ 64;                // k-half 1

  f32x4 acc[8][4];
#pragma unroll
  for (int i = 0; i < 8; ++i)
#pragma unroll
    for (int j = 0; j < 4; ++j) acc[i][j] = (f32x4){0.f, 0.f, 0.f, 0.f};
  bf16x8 af[4][2], bfr[2][2];

  // ---- prologue: half-tiles 0..6 (tile0 full + tile1 q0,q1,q2) ----
  STAGE_A(0, 0, 0); STAGE_B(0, 0, 1); STAGE_A(0, 0, 1); STAGE_B(0, 0, 0);
  STAGE_A(1, 1, 0); STAGE_B(1, 1, 1); STAGE_A(1, 1, 1);
  asm volatile("s_waitcnt vmcnt(6)" ::: "memory");  // tile0 landed; 3 in flight
  __builtin_amdgcn_s_barrier();
  asm volatile("" ::: "memory");

  // ---- main loop: 12 K-tiles x 4 phases; stage stream s = phase+7 ----
  for (int t = 0; t < 12; ++t) {
    const int buf = t & 1;
    const int nbuf = buf ^ 1;
    // P0 (mh0,nh0): 12 ds_reads; stage B-nh0 of tile t+1 (other buf)
    LOAD_A(buf, 0);
    LOAD_B(buf, 0);
    if (t <= 10) STAGE_B(nbuf, t + 1, 0);
    PH_MID; MFMA_Q(0, 0); PH_END;
    // P1 (mh0,nh1): 4 ds_reads; stage A-mh0 of t+2 (cur buf; freed after P0)
    LOAD_B(buf, 1);
    if (t <= 9) STAGE_A(buf, t + 2, 0);
    PH_MID; MFMA_Q(0, 1); PH_END;
    // P2 (mh1,nh1): 8 ds_reads; stage B-nh1 of t+2 (cur buf; freed after P1)
    LOAD_A(buf, 1);
    if (t <= 9) STAGE_B(buf, t + 2, 1);
    PH_MID; MFMA_Q(1, 1); PH_END;
    // P3 (mh1,nh0): 4 ds_reads; stage A-mh1 of t+2 (cur buf; freed after P2)
    LOAD_B(buf, 0);
    if (t <= 9) STAGE_A(buf, t + 2, 1);
    asm volatile("" ::: "memory");
    __builtin_amdgcn_s_barrier();
    asm volatile("s_waitcnt lgkmcnt(0)" ::: "memory");
    __builtin_amdgcn_s_setprio(1);
    MFMA_Q(1, 0);
    __builtin_amdgcn_s_setprio(0);
    // K-tile boundary: counted wait -- next tile landed, 3 half-tiles in flight
    if (t < 10) {
      asm volatile("s_waitcnt vmcnt(6)" ::: "memory");
    } else if (t == 10) {
      asm volatile("s_waitcnt vmcnt(0)" ::: "memory");
    }
    asm volatile("" ::: "memory");
    __builtin_amdgcn_s_barrier();
    asm volatile("" ::: "memory");
  }

  // ---- epilogue: scale+bias (QSCALE folds 0.125*log2e), LDS-staged stores ----
  const float scale = (widx == 0) ? QSCALE : 1.0f;
  float biasv[4];
#pragma unroll
  for (int nf = 0; nf < 4; ++nf) {
    int n = nb + wn * 64 + nf * 16 + l15;
    biasv[nf] = (widx == 0) ? bq[n] * QSCALE : (widx == 2) ? bv[n] : 0.f;
  }
  u16* E = (u16*)TILES;                    // 256 x 256 u16 (reuses all 128 KiB)
#pragma unroll
  for (int mf = 0; mf < 8; ++mf)
#pragma unroll
    for (int nf = 0; nf < 4; ++nf)
#pragma unroll
      for (int rr = 0; rr < 4; ++rr) {
        int rowl = wm2 * 128 + mf * 16 + quad * 4 + rr;
        int col = wn * 64 + nf * 16 + l15;
        E[rowl * 256 + (col ^ (quad << 4))] =
            f2bf(acc[mf][nf][rr] * scale + biasv[nf]);
      }
  __syncthreads();
  u16* ob = qkv + (size_t)widx * QKV_STRIDE + nb;
#pragma unroll 4
  for (int pass = 0; pass < 16; ++pass) {
    int c = pass * 512 + tid;
    int row = c >> 5, ch = c & 31;
    int m = m0 + row;
    if (m < MTOT) {
      int colr = (ch * 8) ^ (((row >> 2) & 3) << 4);
      *(int4*)(ob + (size_t)m * 768 + ch * 8) = *(const int4*)&E[row * 256 + colr];
    }
  }
}

// ---------------- flash attention (no-max softmax), 512 threads / 128 q-rows ----------------
// grid (bh=192, qt=5): 192%8==0 pins all qt-blocks of one (b,h) to one XCD.
// R15: l = P x ones via 2 extra MFMA/tile. R17: exp2f (scales pre-folded).
// Pad keys carry bias=-144 so they self-mask (2^-144 flushes to 0).
__global__ __launch_bounds__(512) void attn(
    const u16* __restrict__ qk, const u16* __restrict__ vT,
    const u16* __restrict__ biasm, float* __restrict__ out) {
  const int bh = blockIdx.x;  // b*12+h
  const int qt = blockIdx.y;  // 0..4
  const int b = bh / 12, h = bh - b * 12;
  const int tid = threadIdx.x;
  const int lane = tid & 63;
  const int w = tid >> 6;     // 0..7
  const int quad = lane >> 4;
  const int l15 = lane & 15;

  const u16* qp = qk + (size_t)b * SEQ * 768 + h * 64;  // row stride 768
  const u16* kp = qp + (size_t)QKV_STRIDE;
  const u16* vtp = vT + (size_t)bh * 64 * VT_PITCH;
  const u16* bp = biasm + (size_t)h * SEQ * B_PITCH;

  __shared__ u16 Ks[64][72];     // [key][d]
  __shared__ u16 VTs[64][72];    // [d][key]
  __shared__ u16 Ps[8][16][72];  // per-wave P tile, XOR-swizzled chunks

  const int qrow0 = qt * 128 + w * 16;

  bf16x8 qf[2];
  {
    int row = qrow0 + l15;
    if (row > 576) row = 576;  // clamp; clamped rows never stored
    qf[0] = *(const bf16x8*)(qp + (size_t)row * 768 + quad * 8);
    qf[1] = *(const bf16x8*)(qp + (size_t)row * 768 + 32 + quad * 8);
  }
  int brow[4];
#pragma unroll
  for (int r = 0; r < 4; ++r) {
    int rr = qrow0 + quad * 4 + r;
    if (rr > 576) rr = 576;
    brow[r] = rr;
  }

  const short one_bf = (short)0x3F80;      // bf16 1.0
  const bf16x8 vones = {one_bf, one_bf, one_bf, one_bf,
                        one_bf, one_bf, one_bf, one_bf};

  f32x4 Ol = (f32x4){0.f, 0.f, 0.f, 0.f};  // row sums l (per quad-row)
  f32x4 O[4];
#pragma unroll
  for (int dt = 0; dt < 4; ++dt) O[dt] = (f32x4){0.f, 0.f, 0.f, 0.f};

  for (int kt = 0; kt < 10; ++kt) {
    const int kbase = kt * 64;
    // bias loads first (independent VMEM, latency overlaps staging)
    u16 bb[4][4];
#pragma unroll
    for (int nt = 0; nt < 4; ++nt)
#pragma unroll
      for (int r = 0; r < 4; ++r)
        bb[nt][r] = bp[(size_t)brow[r] * B_PITCH + kbase + nt * 16 + l15];

    // stage K [key][d] and V^T window [d][key] — 512 threads = one pass each
    {
      int rr = tid >> 3, ko = (tid & 7) << 3;
      int gk = kbase + rr;
      int4 kvv = make_int4(0, 0, 0, 0);
      if (gk < SEQ) kvv = *(const int4*)(kp + (size_t)gk * 768 + ko);
      *(int4*)&Ks[rr][ko] = kvv;
      *(int4*)&VTs[rr][ko] = *(const int4*)(vtp + (size_t)rr * VT_PITCH + kbase + ko);
    }
    __syncthreads();

    // S = Q K^T + bias  (bias as MFMA C-init; q pre-scaled by 0.125*log2e,
    // bias pre-scaled by log2e; pad keys: K=0, bias=-144 -> 2^s = 0)
    f32x4 s[4];
#pragma unroll
    for (int nt = 0; nt < 4; ++nt) {
      f32x4 z = (f32x4){bf2f(bb[nt][0]), bf2f(bb[nt][1]),
                        bf2f(bb[nt][2]), bf2f(bb[nt][3])};
      bf16x8 kf0 = *(const bf16x8*)(&Ks[nt * 16 + l15][quad * 8]);
      bf16x8 kf1 = *(const bf16x8*)(&Ks[nt * 16 + l15][32 + quad * 8]);
      z = __builtin_amdgcn_mfma_f32_16x16x32_bf16(qf[0], kf0, z, 0, 0, 0);
      z = __builtin_amdgcn_mfma_f32_16x16x32_bf16(qf[1], kf1, z, 0, 0, 0);
      s[nt] = z;
    }

    // p = exp2(s); truncate to bf16 into Ps (l comes from ones-MFMA below)
#pragma unroll
    for (int nt = 0; nt < 4; ++nt) {
#pragma unroll
      for (int r = 0; r < 4; ++r) {
        float p = exp2f(s[nt][r]);
        unsigned int u = __float_as_uint(p);
        Ps[w][quad * 4 + r][((nt ^ quad) << 4) + l15] = (u16)(u >> 16);
      }
    }

    // O += P V; Ol += P x ones (row-sum on the matrix pipe)
#pragma unroll
    for (int ks = 0; ks < 2; ++ks) {
      int cc = (ks * 32 + quad * 8) ^ ((l15 >> 2) << 4);
      bf16x8 pf = *(const bf16x8*)(&Ps[w][l15][cc]);
#pragma unroll
      for (int dt = 0; dt < 4; ++dt) {
        bf16x8 vf = *(const bf16x8*)(&VTs[dt * 16 + l15][ks * 32 + quad * 8]);
        O[dt] = __builtin_amdgcn_mfma_f32_16x16x32_bf16(pf, vf, O[dt], 0, 0, 0);
      }
      Ol = __builtin_amdgcn_mfma_f32_16x16x32_bf16(pf, vones, Ol, 0, 0, 0);
    }
    __syncthreads();  // protect Ks/VTs/Ps before next tile's staging
  }

  // epilogue: l available per-lane from the ones-MFMA (no reduction needed)
#pragma unroll
  for (int r = 0; r < 4; ++r) {
    int row = qrow0 + quad * 4 + r;
    if (row < SEQ) {
      float inv = 1.f / Ol[r];
#pragma unroll
      for (int dt = 0; dt < 4; ++dt)
        out[((size_t)(b * SEQ + row)) * 768 + h * 64 + dt * 16 + l15] = O[dt][r] * inv;
    }
  }
}

extern "C" void kernel_launch(void* const* d_in, const int* in_sizes, int n_in,
                              void* d_out, int out_size, void* d_ws, size_t ws_size,
                              hipStream_t stream) {
  const float* hs = (const float*)d_in[0];
  const float* Wq = (const float*)d_in[1];
  const float* bq = (const float*)d_in[2];
  const float* Wk = (const float*)d_in[3];
  const float* Wv = (const float*)d_in[4];
  const float* bv = (const float*)d_in[5];
  const float* table = (const float*)d_in[6];
  const int* idx = (const int*)d_in[7];
  float* out = (float*)d_out;

  char* ws = (char*)d_ws;
  u16* qkv = (u16*)ws;                          // [0, 42541056)
  u16* WT = (u16*)(ws + 42541056);              // phase 1
  u16* Xb = (u16*)(ws + 46080000);              // phase 1
  u16* vT = (u16*)(ws + 42541056);              // phase 2 (over WT + Xb head)
  u16* biasm = (u16*)(ws + 58269696);           // phase 2 (over Xb tail)

  // phase 1: prep (transpose_w + cvt_x) -> GEMM
  hipLaunchKernelGGL(prep, dim3(5190), dim3(256), 0, stream, Wq, Wk, Wv, hs, WT, Xb);
  hipLaunchKernelGGL(qkv_gemm, dim3(360), dim3(512), 0, stream, Xb, WT, bq, bv, qkv);
  // phase 2: prep2 (transpose_v + h-vectorized bias gather) -> attention
  hipLaunchKernelGGL(prep2, dim3(1537), dim3(256), 0, stream,
                     qkv + 2 * (size_t)QKV_STRIDE, vT, table, idx, biasm);
  hipLaunchKernelGGL(attn, dim3(192, 5), dim3(512), 0, stream, qkv, vT, biasm, out);
}

// Round 11
// 199.245 us; speedup vs baseline: 1.0200x; 1.0200x over previous
//
#include <hip/hip_runtime.h>
#include <hip/hip_bf16.h>

// TFData2VecVisionSelfAttention: B=16,S=577,D=768,H=12,HEAD=64. fp32 in/out.
// R20: exp via __builtin_amdgcn_exp2f (raw v_exp_f32, compiler-visible).
// R19's inline-asm v_exp_f32 FAILED (absmax 0.2): CDNA TRANS ops need a
// wait state before the dest VGPR is readable; the hazard recognizer can't
// see inside asm blobs, so consumers issued early and read stale regs.
// The builtin keeps FTZ (masks the -144 pad) and skips OCML's denormal
// fixup (R18: +12 VALUBusy pts) and __expf's extra v_mul (R15).
// qkv_gemm = R10 8-phase 256x256 template (measured 55.3us). prep/prep2 = R17.
// Workspace (bytes, phase-overlapped), total 67.1 MB:
//   qkv   [0, 42541056)                      3 x 9232x768 bf16 m-major (q,k,v)
//   WT    [42541056, 46080000)   phase 1     3x768x768 bf16
//   Xb    [46080000, 60260352)   phase 1     9232x768 bf16
//   vT    [42541056, 58269696)   phase 2     192x64x640 bf16 (over WT+Xb)
//   biasm [58269696, 67132416)   phase 2     12x577x640 bf16 (over Xb tail)

typedef __attribute__((ext_vector_type(8))) short bf16x8;   // 8 x bf16 (4 VGPRs)
typedef __attribute__((ext_vector_type(4))) float f32x4;
typedef unsigned short u16;

#define SEQ 577
#define MTOT 9232            // 16*577
#define QKV_STRIDE 7090176   // 9232*768 elements per q/k/v buffer
#define VT_PITCH 640         // keys per vT row (pad 577..639 zero-filled)
#define B_PITCH 640          // bias row pitch (pad = bf16(-144))
#define QSCALE 0.18033688f   // 0.125 * log2(e)
#define LOG2E 1.44269504f

// fp32 -> bf16 round-to-nearest-even
static __device__ __forceinline__ u16 f2bf(float x) {
  unsigned int u = __float_as_uint(x);
  u = (u + 0x7FFFu + ((u >> 16) & 1u)) >> 16;
  return (u16)u;
}
static __device__ __forceinline__ float bf2f(u16 v) {
  return __uint_as_float(((unsigned int)v) << 16);
}

// async global->LDS, 16B per lane; LDS dest = wave-uniform base + lane*16
static __device__ __forceinline__ void gload_lds16(const void* g, void* l) {
  __builtin_amdgcn_global_load_lds(
      (const __attribute__((address_space(1))) unsigned int*)g,
      (__attribute__((address_space(3))) unsigned int*)l, 16, 0, 0);
}

// ---------------- prep: transpose_w (blocks 0..1727) + cvt_x (1728..5189) ----------------
__global__ __launch_bounds__(256) void prep(
    const float* __restrict__ Wq, const float* __restrict__ Wk,
    const float* __restrict__ Wv, const float* __restrict__ X,
    u16* __restrict__ WT, u16* __restrict__ Xb) {
  const int bid = blockIdx.x;
  if (bid < 1728) {
    __shared__ float t[32][33];
    const int z = bid / 576;
    const int rem = bid - z * 576;
    const int kx = rem % 24, ny = rem / 24;
    const float* W = (z == 0) ? Wq : (z == 1) ? Wk : Wv;
    int x = threadIdx.x & 31;
    int y = threadIdx.x >> 5;  // 0..7
    int k0 = kx * 32;
    int n0 = ny * 32;
#pragma unroll
    for (int i = 0; i < 4; ++i)
      t[y + i * 8][x] = W[(size_t)(k0 + y + i * 8) * 768 + n0 + x];
    __syncthreads();
    u16* o = WT + (size_t)z * 589824;
#pragma unroll
    for (int i = 0; i < 4; ++i)
      o[(size_t)(n0 + y + i * 8) * 768 + k0 + x] = f2bf(t[x][y + i * 8]);
  } else {
    size_t i = ((size_t)(bid - 1728) * 256 + threadIdx.x) * 8;
    if (i >= (size_t)MTOT * 768) return;
    const float4* xp = (const float4*)(X + i);
    float4 a = xp[0], b = xp[1];
    u16 pk[8] = {f2bf(a.x), f2bf(a.y), f2bf(a.z), f2bf(a.w),
                 f2bf(b.x), f2bf(b.y), f2bf(b.z), f2bf(b.w)};
    *(int4*)(Xb + i) = *(const int4*)pk;
  }
}

// ---------------- prep2: transpose_v (blocks 0..959) + bias_pre (960..1536) ----------------
__global__ __launch_bounds__(256) void prep2(
    const u16* __restrict__ v,      // v buffer, [m][768]
    u16* __restrict__ vT,           // [bh][64][640]
    const float* __restrict__ table, const int* __restrict__ idx,
    u16* __restrict__ biasm) {
  const int bid = blockIdx.x;
  const int tid = threadIdx.x;
  if (bid < 960) {
    const int tile = bid % 5;   // s0 = tile*128
    const int bh = bid / 5;     // 0..191
    const int b = bh / 12, h = bh % 12;
    __shared__ u16 T[128][64];
    const int s0 = tile * 128;
    const u16* vp = v + (size_t)b * SEQ * 768 + h * 64;
#pragma unroll
    for (int it = 0; it < 4; ++it) {
      int c = tid + it * 256;          // 1024 chunks of 16B
      int r = c >> 3, ko = (c & 7) << 3;
      int gs = s0 + r;
      int4 val = make_int4(0, 0, 0, 0);
      if (gs < SEQ) val = *(const int4*)(vp + (size_t)gs * 768 + ko);
      *(int4*)&T[r][ko ^ (((r >> 3) & 7) << 3)] = val;  // swizzled store
    }
    __syncthreads();
    u16* op = vT + (size_t)bh * 64 * VT_PITCH;
#pragma unroll
    for (int it = 0; it < 4; ++it) {
      int c = tid + it * 256;          // d = c>>4, so = (c&15)*8
      int d = c >> 4, so = (c & 15) << 3;
      u16 tmp[8];
#pragma unroll
      for (int j = 0; j < 8; ++j) {
        int rr = so + j;
        tmp[j] = T[rr][d ^ (((rr >> 3) & 7) << 3)];
      }
      *(int4*)(op + (size_t)d * VT_PITCH + s0 + so) = *(const int4*)tmp;
    }
  } else {
    // bias gather, h-vectorized: one block per q-row. idx read once per
    // (q,k); table row (12 floats = 48B) via 3x float4; values pre-scaled
    // by log2e for attn's exp2. 12 coalesced u16 plane-stores.
    const int q = bid - 960;        // 0..576
    const int* idxq = idx + q * SEQ;
    const u16 pad = f2bf(-144.0f);
    for (int k = tid; k < B_PITCH; k += 256) {
      u16 vv[12];
      if (k < SEQ) {
        const float4* tp = (const float4*)(table + (size_t)idxq[k] * 12);
        float4 t0 = tp[0], t1 = tp[1], t2 = tp[2];
        vv[0] = f2bf(t0.x * LOG2E);  vv[1] = f2bf(t0.y * LOG2E);
        vv[2] = f2bf(t0.z * LOG2E);  vv[3] = f2bf(t0.w * LOG2E);
        vv[4] = f2bf(t1.x * LOG2E);  vv[5] = f2bf(t1.y * LOG2E);
        vv[6] = f2bf(t1.z * LOG2E);  vv[7] = f2bf(t1.w * LOG2E);
        vv[8] = f2bf(t2.x * LOG2E);  vv[9] = f2bf(t2.y * LOG2E);
        vv[10] = f2bf(t2.z * LOG2E); vv[11] = f2bf(t2.w * LOG2E);
      } else {
#pragma unroll
        for (int h = 0; h < 12; ++h) vv[h] = pad;  // pad keys self-mask
      }
#pragma unroll
      for (int h = 0; h < 12; ++h)
        biasm[((size_t)h * SEQ + q) * B_PITCH + k] = vv[h];
    }
  }
}

// ---------------- fused QKV GEMM: 256x256 tile, BK=64, 8 waves, 8-phase ----------------
// R10 template (measured 55.3us): grid 37 M-tiles x 9 N-tiles, mt pinned to
// XCD. LDS TILES[2 dbuf][A,B][256][64] = 128 KiB, st-16-style XOR swizzle
// (linear gload_lds dest + inverse-swizzled global src + swizzled ds_read).
// 4 phases per K-tile {ds_read quadrant | stage 1 half-tile -> barrier ->
// lgkmcnt(0) -> setprio(1) -> 16 MFMA -> setprio(0) -> barrier}; counted
// s_waitcnt vmcnt(6) only at K-tile boundaries (3 half-tiles in flight).
#define STAGE_A(BUF, KT, MH)                                                   \
  do {                                                                         \
    gload_lds16(asrc[(MH)] + (KT) * 64, &TILES[(BUF)][0][(MH) * 64 + w8][0]);  \
    gload_lds16(asrc[(MH) + 2] + (KT) * 64,                                    \
                &TILES[(BUF)][0][128 + (MH) * 64 + w8][0]);                    \
  } while (0)

#define STAGE_B(BUF, KT, NH)                                                   \
  do {                                                                         \
    gload_lds16(bsrc + (size_t)((NH) * 32) * 768 + (KT) * 64,                  \
                &TILES[(BUF)][1][bw + (NH) * 32][0]);                          \
    gload_lds16(bsrc + (size_t)(128 + (NH) * 32) * 768 + (KT) * 64,            \
                &TILES[(BUF)][1][128 + bw + (NH) * 32][0]);                    \
  } while (0)

#define LOAD_A(BUF, MH)                                                        \
  do {                                                                         \
    const char* _p =                                                           \
        (const char*)&TILES[(BUF)][0][wm2 * 128 + (MH) * 64 + l15][0];         \
    af[0][0] = *(const bf16x8*)(_p + ca0);                                     \
    af[0][1] = *(const bf16x8*)(_p + ca1);                                     \
    af[1][0] = *(const bf16x8*)(_p + 2048 + ca0);                              \
    af[1][1] = *(const bf16x8*)(_p + 2048 + ca1);                              \
    af[2][0] = *(const bf16x8*)(_p + 4096 + ca0);                              \
    af[2][1] = *(const bf16x8*)(_p + 4096 + ca1);                              \
    af[3][0] = *(const bf16x8*)(_p + 6144 + ca0);                              \
    af[3][1] = *(const bf16x8*)(_p + 6144 + ca1);                              \
  } while (0)

#define LOAD_B(BUF, NH)                                                        \
  do {                                                                         \
    const char* _p =                                                           \
        (const char*)&TILES[(BUF)][1][wn * 64 + (NH) * 32 + l15][0];           \
    bfr[0][0] = *(const bf16x8*)(_p + ca0);                                    \
    bfr[0][1] = *(const bf16x8*)(_p + ca1);                                    \
    bfr[1][0] = *(const bf16x8*)(_p + 2048 + ca0);                             \
    bfr[1][1] = *(const bf16x8*)(_p + 2048 + ca1);                             \
  } while (0)

#define MFMA_Q(MH, NH)                                                         \
  do {                                                                         \
    _Pragma("unroll") for (int _i = 0; _i < 4; ++_i)                           \
        _Pragma("unroll") for (int _j = 0; _j < 2; ++_j)                       \
            acc[(MH) * 4 + _i][(NH) * 2 + _j] =                                \
        __builtin_amdgcn_mfma_f32_16x16x32_bf16(                               \
            af[_i][0], bfr[_j][0], acc[(MH) * 4 + _i][(NH) * 2 + _j], 0, 0,    \
            0);                                                                \
    _Pragma("unroll") for (int _i = 0; _i < 4; ++_i)                           \
        _Pragma("unroll") for (int _j = 0; _j < 2; ++_j)                       \
            acc[(MH) * 4 + _i][(NH) * 2 + _j] =                                \
        __builtin_amdgcn_mfma_f32_16x16x32_bf16(                               \
            af[_i][1], bfr[_j][1], acc[(MH) * 4 + _i][(NH) * 2 + _j], 0, 0,    \
            0);                                                                \
  } while (0)

#define PH_MID                                                                 \
  do {                                                                         \
    asm volatile("" ::: "memory");                                             \
    __builtin_amdgcn_s_barrier();                                              \
    asm volatile("s_waitcnt lgkmcnt(0)" ::: "memory");                         \
    __builtin_amdgcn_s_setprio(1);                                             \
  } while (0)

#define PH_END                                                                 \
  do {                                                                         \
    __builtin_amdgcn_s_setprio(0);                                             \
    asm volatile("" ::: "memory");                                             \
    __builtin_amdgcn_s_barrier();                                              \
    asm volatile("" ::: "memory");                                             \
  } while (0)

__global__ __launch_bounds__(512, 2) void qkv_gemm(
    const u16* __restrict__ Xb,   // [9232][768] bf16
    const u16* __restrict__ WT,   // [3][768][768] n-major bf16
    const float* __restrict__ bq, const float* __restrict__ bv,
    u16* __restrict__ qkv) {
  const int bid = blockIdx.x;
  const int xcd = bid & 7;
  const int r8 = bid >> 3;                 // 0..44
  const int mt = (r8 / 9) * 8 + xcd;       // all 9 nt of one mt -> same XCD
  if (mt >= 37) return;
  const int nt = r8 % 9;
  const int m0 = mt * 256;
  const int widx = nt / 3;                 // 0=q, 1=k, 2=v
  const int nb = (nt % 3) * 256;           // col base within [0,768)

  const int tid = threadIdx.x;
  const int lane = tid & 63;
  const int w = tid >> 6;                  // 0..7
  const int wm2 = w >> 2;                  // 0..1 (M half)
  const int wn = w & 3;                    // 0..3 (N quarter)
  const int quad = lane >> 4;
  const int l15 = lane & 15;

  __shared__ u16 TILES[2][2][256][64];     // 128 KiB

  // ---- staging addressing (per-lane swizzled global src, per-wave LDS base)
  const int lr = lane >> 3;                // row within an 8-row group
  const int w8 = w * 8;
  const int ce = ((lane & 7) ^ lr) * 8;    // swizzled src element offset
  const u16* asrc[4];                      // A chunk row bases 0/64/128/192
#pragma unroll
  for (int c = 0; c < 4; ++c) {
    int rr = m0 + c * 64 + w8 + lr;
    if (rr > MTOT - 1) rr = MTOT - 1;      // clamped rows: garbage, not stored
    asrc[c] = Xb + (size_t)rr * 768 + ce;
  }
  const int bw = (w >> 2) * 64 + (w & 3) * 8;
  const u16* bsrc = WT + (size_t)widx * 589824 + (size_t)(nb + bw + lr) * 768 + ce;

  // ---- ds_read addressing (swizzled) ----
  const int lswz = (l15 & 7) << 4;
  const int ca0 = (quad * 16) ^ lswz;      // k-half 0
  const int ca1 = ca0 ^ 64;                // k-half 1

  f32x4 acc[8][4];
#pragma unroll
  for (int i = 0; i < 8; ++i)
#pragma unroll
    for (int j = 0; j < 4; ++j) acc[i][j] = (f32x4){0.f, 0.f, 0.f, 0.f};
  bf16x8 af[4][2], bfr[2][2];

  // ---- prologue: half-tiles 0..6 (tile0 full + tile1 q0,q1,q2) ----
  STAGE_A(0, 0, 0); STAGE_B(0, 0, 1); STAGE_A(0, 0, 1); STAGE_B(0, 0, 0);
  STAGE_A(1, 1, 0); STAGE_B(1, 1, 1); STAGE_A(1, 1, 1);
  asm volatile("s_waitcnt vmcnt(6)" ::: "memory");  // tile0 landed; 3 in flight
  __builtin_amdgcn_s_barrier();
  asm volatile("" ::: "memory");

  // ---- main loop: 12 K-tiles x 4 phases; stage stream s = phase+7 ----
  for (int t = 0; t < 12; ++t) {
    const int buf = t & 1;
    const int nbuf = buf ^ 1;
    // P0 (mh0,nh0): 12 ds_reads; stage B-nh0 of tile t+1 (other buf)
    LOAD_A(buf, 0);
    LOAD_B(buf, 0);
    if (t <= 10) STAGE_B(nbuf, t + 1, 0);
    PH_MID; MFMA_Q(0, 0); PH_END;
    // P1 (mh0,nh1): 4 ds_reads; stage A-mh0 of t+2 (cur buf; freed after P0)
    LOAD_B(buf, 1);
    if (t <= 9) STAGE_A(buf, t + 2, 0);
    PH_MID; MFMA_Q(0, 1); PH_END;
    // P2 (mh1,nh1): 8 ds_reads; stage B-nh1 of t+2 (cur buf; freed after P1)
    LOAD_A(buf, 1);
    if (t <= 9) STAGE_B(buf, t + 2, 1);
    PH_MID; MFMA_Q(1, 1); PH_END;
    // P3 (mh1,nh0): 4 ds_reads; stage A-mh1 of t+2 (cur buf; freed after P2)
    LOAD_B(buf, 0);
    if (t <= 9) STAGE_A(buf, t + 2, 1);
    asm volatile("" ::: "memory");
    __builtin_amdgcn_s_barrier();
    asm volatile("s_waitcnt lgkmcnt(0)" ::: "memory");
    __builtin_amdgcn_s_setprio(1);
    MFMA_Q(1, 0);
    __builtin_amdgcn_s_setprio(0);
    // K-tile boundary: counted wait -- next tile landed, 3 half-tiles in flight
    if (t < 10) {
      asm volatile("s_waitcnt vmcnt(6)" ::: "memory");
    } else if (t == 10) {
      asm volatile("s_waitcnt vmcnt(0)" ::: "memory");
    }
    asm volatile("" ::: "memory");
    __builtin_amdgcn_s_barrier();
    asm volatile("" ::: "memory");
  }

  // ---- epilogue: scale+bias (QSCALE folds 0.125*log2e), LDS-staged stores ----
  const float scale = (widx == 0) ? QSCALE : 1.0f;
  float biasv[4];
#pragma unroll
  for (int nf = 0; nf < 4; ++nf) {
    int n = nb + wn * 64 + nf * 16 + l15;
    biasv[nf] = (widx == 0) ? bq[n] * QSCALE : (widx == 2) ? bv[n] : 0.f;
  }
  u16* E = (u16*)TILES;                    // 256 x 256 u16 (reuses all 128 KiB)
#pragma unroll
  for (int mf = 0; mf < 8; ++mf)
#pragma unroll
    for (int nf = 0; nf < 4; ++nf)
#pragma unroll
      for (int rr = 0; rr < 4; ++rr) {
        int rowl = wm2 * 128 + mf * 16 + quad * 4 + rr;
        int col = wn * 64 + nf * 16 + l15;
        E[rowl * 256 + (col ^ (quad << 4))] =
            f2bf(acc[mf][nf][rr] * scale + biasv[nf]);
      }
  __syncthreads();
  u16* ob = qkv + (size_t)widx * QKV_STRIDE + nb;
#pragma unroll 4
  for (int pass = 0; pass < 16; ++pass) {
    int c = pass * 512 + tid;
    int row = c >> 5, ch = c & 31;
    int m = m0 + row;
    if (m < MTOT) {
      int colr = (ch * 8) ^ (((row >> 2) & 3) << 4);
      *(int4*)(ob + (size_t)m * 768 + ch * 8) = *(const int4*)&E[row * 256 + colr];
    }
  }
}

// ---------------- flash attention (no-max softmax), 512 threads / 128 q-rows ----------------
// grid (bh=192, qt=5): 192%8==0 pins all qt-blocks of one (b,h) to one XCD.
// R15: l = P x ones via 2 extra MFMA/tile. R20: __builtin_amdgcn_exp2f
// (raw v_exp_f32, hazard-safe; FTZ masks the -144 pad exactly as intended).
__global__ __launch_bounds__(512) void attn(
    const u16* __restrict__ qk, const u16* __restrict__ vT,
    const u16* __restrict__ biasm, float* __restrict__ out) {
  const int bh = blockIdx.x;  // b*12+h
  const int qt = blockIdx.y;  // 0..4
  const int b = bh / 12, h = bh - b * 12;
  const int tid = threadIdx.x;
  const int lane = tid & 63;
  const int w = tid >> 6;     // 0..7
  const int quad = lane >> 4;
  const int l15 = lane & 15;

  const u16* qp = qk + (size_t)b * SEQ * 768 + h * 64;  // row stride 768
  const u16* kp = qp + (size_t)QKV_STRIDE;
  const u16* vtp = vT + (size_t)bh * 64 * VT_PITCH;
  const u16* bp = biasm + (size_t)h * SEQ * B_PITCH;

  __shared__ u16 Ks[64][72];     // [key][d]
  __shared__ u16 VTs[64][72];    // [d][key]
  __shared__ u16 Ps[8][16][72];  // per-wave P tile, XOR-swizzled chunks

  const int qrow0 = qt * 128 + w * 16;

  bf16x8 qf[2];
  {
    int row = qrow0 + l15;
    if (row > 576) row = 576;  // clamp; clamped rows never stored
    qf[0] = *(const bf16x8*)(qp + (size_t)row * 768 + quad * 8);
    qf[1] = *(const bf16x8*)(qp + (size_t)row * 768 + 32 + quad * 8);
  }
  int brow[4];
#pragma unroll
  for (int r = 0; r < 4; ++r) {
    int rr = qrow0 + quad * 4 + r;
    if (rr > 576) rr = 576;
    brow[r] = rr;
  }

  const short one_bf = (short)0x3F80;      // bf16 1.0
  const bf16x8 vones = {one_bf, one_bf, one_bf, one_bf,
                        one_bf, one_bf, one_bf, one_bf};

  f32x4 Ol = (f32x4){0.f, 0.f, 0.f, 0.f};  // row sums l (per quad-row)
  f32x4 O[4];
#pragma unroll
  for (int dt = 0; dt < 4; ++dt) O[dt] = (f32x4){0.f, 0.f, 0.f, 0.f};

  for (int kt = 0; kt < 10; ++kt) {
    const int kbase = kt * 64;
    // bias loads first (independent VMEM, latency overlaps staging)
    u16 bb[4][4];
#pragma unroll
    for (int nt = 0; nt < 4; ++nt)
#pragma unroll
      for (int r = 0; r < 4; ++r)
        bb[nt][r] = bp[(size_t)brow[r] * B_PITCH + kbase + nt * 16 + l15];

    // stage K [key][d] and V^T window [d][key] — 512 threads = one pass each
    {
      int rr = tid >> 3, ko = (tid & 7) << 3;
      int gk = kbase + rr;
      int4 kvv = make_int4(0, 0, 0, 0);
      if (gk < SEQ) kvv = *(const int4*)(kp + (size_t)gk * 768 + ko);
      *(int4*)&Ks[rr][ko] = kvv;
      *(int4*)&VTs[rr][ko] = *(const int4*)(vtp + (size_t)rr * VT_PITCH + kbase + ko);
    }
    __syncthreads();

    // S = Q K^T + bias  (bias as MFMA C-init; q pre-scaled by 0.125*log2e,
    // bias pre-scaled by log2e; pad keys: K=0, bias=-144 -> 2^s = 0)
    f32x4 s[4];
#pragma unroll
    for (int nt = 0; nt < 4; ++nt) {
      f32x4 z = (f32x4){bf2f(bb[nt][0]), bf2f(bb[nt][1]),
                        bf2f(bb[nt][2]), bf2f(bb[nt][3])};
      bf16x8 kf0 = *(const bf16x8*)(&Ks[nt * 16 + l15][quad * 8]);
      bf16x8 kf1 = *(const bf16x8*)(&Ks[nt * 16 + l15][32 + quad * 8]);
      z = __builtin_amdgcn_mfma_f32_16x16x32_bf16(qf[0], kf0, z, 0, 0, 0);
      z = __builtin_amdgcn_mfma_f32_16x16x32_bf16(qf[1], kf1, z, 0, 0, 0);
      s[nt] = z;
    }

    // p = 2^s via raw v_exp_f32 (builtin); truncate to bf16 into Ps
#pragma unroll
    for (int nt = 0; nt < 4; ++nt) {
#pragma unroll
      for (int r = 0; r < 4; ++r) {
        float p = __builtin_amdgcn_exp2f(s[nt][r]);
        unsigned int u = __float_as_uint(p);
        Ps[w][quad * 4 + r][((nt ^ quad) << 4) + l15] = (u16)(u >> 16);
      }
    }

    // O += P V; Ol += P x ones (row-sum on the matrix pipe)
#pragma unroll
    for (int ks = 0; ks < 2; ++ks) {
      int cc = (ks * 32 + quad * 8) ^ ((l15 >> 2) << 4);
      bf16x8 pf = *(const bf16x8*)(&Ps[w][l15][cc]);
#pragma unroll
      for (int dt = 0; dt < 4; ++dt) {
        bf16x8 vf = *(const bf16x8*)(&VTs[dt * 16 + l15][ks * 32 + quad * 8]);
        O[dt] = __builtin_amdgcn_mfma_f32_16x16x32_bf16(pf, vf, O[dt], 0, 0, 0);
      }
      Ol = __builtin_amdgcn_mfma_f32_16x16x32_bf16(pf, vones, Ol, 0, 0, 0);
    }
    __syncthreads();  // protect Ks/VTs/Ps before next tile's staging
  }

  // epilogue: l available per-lane from the ones-MFMA (no reduction needed)
#pragma unroll
  for (int r = 0; r < 4; ++r) {
    int row = qrow0 + quad * 4 + r;
    if (row < SEQ) {
      float inv = 1.f / Ol[r];
#pragma unroll
      for (int dt = 0; dt < 4; ++dt)
        out[((size_t)(b * SEQ + row)) * 768 + h * 64 + dt * 16 + l15] = O[dt][r] * inv;
    }
  }
}

extern "C" void kernel_launch(void* const* d_in, const int* in_sizes, int n_in,
                              void* d_out, int out_size, void* d_ws, size_t ws_size,
                              hipStream_t stream) {
  const float* hs = (const float*)d_in[0];
  const float* Wq = (const float*)d_in[1];
  const float* bq = (const float*)d_in[2];
  const float* Wk = (const float*)d_in[3];
  const float* Wv = (const float*)d_in[4];
  const float* bv = (const float*)d_in[5];
  const float* table = (const float*)d_in[6];
  const int* idx = (const int*)d_in[7];
  float* out = (float*)d_out;

  char* ws = (char*)d_ws;
  u16* qkv = (u16*)ws;                          // [0, 42541056)
  u16* WT = (u16*)(ws + 42541056);              // phase 1
  u16* Xb = (u16*)(ws + 46080000);              // phase 1
  u16* vT = (u16*)(ws + 42541056);              // phase 2 (over WT + Xb head)
  u16* biasm = (u16*)(ws + 58269696);           // phase 2 (over Xb tail)

  // phase 1: prep (transpose_w + cvt_x) -> GEMM
  hipLaunchKernelGGL(prep, dim3(5190), dim3(256), 0, stream, Wq, Wk, Wv, hs, WT, Xb);
  hipLaunchKernelGGL(qkv_gemm, dim3(360), dim3(512), 0, stream, Xb, WT, bq, bv, qkv);
  // phase 2: prep2 (transpose_v + h-vectorized bias gather) -> attention
  hipLaunchKernelGGL(prep2, dim3(1537), dim3(256), 0, stream,
                     qkv + 2 * (size_t)QKV_STRIDE, vT, table, idx, biasm);
  hipLaunchKernelGGL(attn, dim3(192, 5), dim3(512), 0, stream, qkv, vT, biasm, out);
}

// Round 12
// 199.109 us; speedup vs baseline: 1.0207x; 1.0007x over previous
//
#include <hip/hip_runtime.h>
#include <hip/hip_bf16.h>

// TFData2VecVisionSelfAttention: B=16,S=577,D=768,H=12,HEAD=64. fp32 in/out.
// R21: attn bias path vectorized via transposed biasT[h][key 577][q 584]:
// one 8B short4 per nt (4 loads/lane/tile) instead of 16 scalar 2B gathers.
// This is R12's layout idea done RIGHT: no cross-iteration prefetch state
// (R12's real regression: VGPR 44->112 halved occupancy), clamp base to 576
// (R12's bug: clamped to 572, corrupting row 576's bias), pad keys >576
// handled by a uniform-branch select to -144 on the LAST tile only (so no
// stored pad rows; biasT = 8.09 MB fits the old biasm slot).
// attn exp = __builtin_amdgcn_exp2f (R20); l = P x ones MFMA (R15).
// qkv_gemm = R10 8-phase 256x256 template (measured 54.7us). prep = R17.
// Workspace (bytes, phase-overlapped), total 67.1 MB:
//   qkv   [0, 42541056)                      3 x 9232x768 bf16 m-major (q,k,v)
//   WT    [42541056, 46080000)   phase 1     3x768x768 bf16
//   Xb    [46080000, 60260352)   phase 1     9232x768 bf16
//   vT    [42541056, 58269696)   phase 2     192x64x640 bf16 (over WT+Xb)
//   biasT [58269696, 66356928)   phase 2     12x577x584 bf16 [h][key][qrow]

typedef __attribute__((ext_vector_type(8))) short bf16x8;   // 8 x bf16 (4 VGPRs)
typedef __attribute__((ext_vector_type(4))) float f32x4;
typedef unsigned short u16;

#define SEQ 577
#define MTOT 9232            // 16*577
#define QKV_STRIDE 7090176   // 9232*768 elements per q/k/v buffer
#define VT_PITCH 640         // keys per vT row (pad 577..639 zero-filled)
#define BT_K 577             // biasT key rows (no pad; last tile uses select)
#define BT_Q 584             // biasT qrow pitch (577..583 zero pad, mult of 4)
#define QSCALE 0.18033688f   // 0.125 * log2(e)
#define LOG2E 1.44269504f

// fp32 -> bf16 round-to-nearest-even
static __device__ __forceinline__ u16 f2bf(float x) {
  unsigned int u = __float_as_uint(x);
  u = (u + 0x7FFFu + ((u >> 16) & 1u)) >> 16;
  return (u16)u;
}
static __device__ __forceinline__ float bf2f(u16 v) {
  return __uint_as_float(((unsigned int)v) << 16);
}

// async global->LDS, 16B per lane; LDS dest = wave-uniform base + lane*16
static __device__ __forceinline__ void gload_lds16(const void* g, void* l) {
  __builtin_amdgcn_global_load_lds(
      (const __attribute__((address_space(1))) unsigned int*)g,
      (__attribute__((address_space(3))) unsigned int*)l, 16, 0, 0);
}

// ---------------- prep: transpose_w (blocks 0..1727) + cvt_x (1728..5189) ----------------
__global__ __launch_bounds__(256) void prep(
    const float* __restrict__ Wq, const float* __restrict__ Wk,
    const float* __restrict__ Wv, const float* __restrict__ X,
    u16* __restrict__ WT, u16* __restrict__ Xb) {
  const int bid = blockIdx.x;
  if (bid < 1728) {
    __shared__ float t[32][33];
    const int z = bid / 576;
    const int rem = bid - z * 576;
    const int kx = rem % 24, ny = rem / 24;
    const float* W = (z == 0) ? Wq : (z == 1) ? Wk : Wv;
    int x = threadIdx.x & 31;
    int y = threadIdx.x >> 5;  // 0..7
    int k0 = kx * 32;
    int n0 = ny * 32;
#pragma unroll
    for (int i = 0; i < 4; ++i)
      t[y + i * 8][x] = W[(size_t)(k0 + y + i * 8) * 768 + n0 + x];
    __syncthreads();
    u16* o = WT + (size_t)z * 589824;
#pragma unroll
    for (int i = 0; i < 4; ++i)
      o[(size_t)(n0 + y + i * 8) * 768 + k0 + x] = f2bf(t[x][y + i * 8]);
  } else {
    size_t i = ((size_t)(bid - 1728) * 256 + threadIdx.x) * 8;
    if (i >= (size_t)MTOT * 768) return;
    const float4* xp = (const float4*)(X + i);
    float4 a = xp[0], b = xp[1];
    u16 pk[8] = {f2bf(a.x), f2bf(a.y), f2bf(a.z), f2bf(a.w),
                 f2bf(b.x), f2bf(b.y), f2bf(b.z), f2bf(b.w)};
    *(int4*)(Xb + i) = *(const int4*)pk;
  }
}

// ---------------- prep2: transpose_v (blocks 0..959) + biasT gather (960..1536) ----------------
__global__ __launch_bounds__(256) void prep2(
    const u16* __restrict__ v,      // v buffer, [m][768]
    u16* __restrict__ vT,           // [bh][64][640]
    const float* __restrict__ table, const int* __restrict__ idx,
    u16* __restrict__ biasT) {      // [h][key BT_K][qrow BT_Q]
  const int bid = blockIdx.x;
  const int tid = threadIdx.x;
  if (bid < 960) {
    const int tile = bid % 5;   // s0 = tile*128
    const int bh = bid / 5;     // 0..191
    const int b = bh / 12, h = bh % 12;
    __shared__ u16 T[128][64];
    const int s0 = tile * 128;
    const u16* vp = v + (size_t)b * SEQ * 768 + h * 64;
#pragma unroll
    for (int it = 0; it < 4; ++it) {
      int c = tid + it * 256;          // 1024 chunks of 16B
      int r = c >> 3, ko = (c & 7) << 3;
      int gs = s0 + r;
      int4 val = make_int4(0, 0, 0, 0);
      if (gs < SEQ) val = *(const int4*)(vp + (size_t)gs * 768 + ko);
      *(int4*)&T[r][ko ^ (((r >> 3) & 7) << 3)] = val;  // swizzled store
    }
    __syncthreads();
    u16* op = vT + (size_t)bh * 64 * VT_PITCH;
#pragma unroll
    for (int it = 0; it < 4; ++it) {
      int c = tid + it * 256;          // d = c>>4, so = (c&15)*8
      int d = c >> 4, so = (c & 15) << 3;
      u16 tmp[8];
#pragma unroll
      for (int j = 0; j < 8; ++j) {
        int rr = so + j;
        tmp[j] = T[rr][d ^ (((rr >> 3) & 7) << 3)];
      }
      *(int4*)(op + (size_t)d * VT_PITCH + s0 + so) = *(const int4*)tmp;
    }
  } else {
    // biasT gather: one block per key k. idx[q][k] read per thread (column,
    // L2-backed, read once total); table row (48B) via 3x float4; values
    // pre-scaled by log2e. Stores q-contiguous -> coalesced per h-plane.
    const int k = bid - 960;        // 0..576
    for (int q = tid; q < BT_Q; q += 256) {
      u16 vv[12];
      if (q < SEQ) {
        const float4* tp =
            (const float4*)(table + (size_t)idx[(size_t)q * SEQ + k] * 12);
        float4 t0 = tp[0], t1 = tp[1], t2 = tp[2];
        vv[0] = f2bf(t0.x * LOG2E);  vv[1] = f2bf(t0.y * LOG2E);
        vv[2] = f2bf(t0.z * LOG2E);  vv[3] = f2bf(t0.w * LOG2E);
        vv[4] = f2bf(t1.x * LOG2E);  vv[5] = f2bf(t1.y * LOG2E);
        vv[6] = f2bf(t1.z * LOG2E);  vv[7] = f2bf(t1.w * LOG2E);
        vv[8] = f2bf(t2.x * LOG2E);  vv[9] = f2bf(t2.y * LOG2E);
        vv[10] = f2bf(t2.z * LOG2E); vv[11] = f2bf(t2.w * LOG2E);
      } else {
#pragma unroll
        for (int h = 0; h < 12; ++h) vv[h] = 0;  // q-pad, never stored
      }
#pragma unroll
      for (int h = 0; h < 12; ++h)
        biasT[((size_t)h * BT_K + k) * BT_Q + q] = vv[h];
    }
  }
}

// ---------------- fused QKV GEMM: 256x256 tile, BK=64, 8 waves, 8-phase ----------------
// R10 template (measured 54.7us): grid 37 M-tiles x 9 N-tiles, mt pinned to
// XCD. LDS TILES[2 dbuf][A,B][256][64] = 128 KiB, st-16-style XOR swizzle
// (linear gload_lds dest + inverse-swizzled global src + swizzled ds_read).
// 4 phases per K-tile {ds_read quadrant | stage 1 half-tile -> barrier ->
// lgkmcnt(0) -> setprio(1) -> 16 MFMA -> setprio(0) -> barrier}; counted
// s_waitcnt vmcnt(6) only at K-tile boundaries (3 half-tiles in flight).
#define STAGE_A(BUF, KT, MH)                                                   \
  do {                                                                         \
    gload_lds16(asrc[(MH)] + (KT) * 64, &TILES[(BUF)][0][(MH) * 64 + w8][0]);  \
    gload_lds16(asrc[(MH) + 2] + (KT) * 64,                                    \
                &TILES[(BUF)][0][128 + (MH) * 64 + w8][0]);                    \
  } while (0)

#define STAGE_B(BUF, KT, NH)                                                   \
  do {                                                                         \
    gload_lds16(bsrc + (size_t)((NH) * 32) * 768 + (KT) * 64,                  \
                &TILES[(BUF)][1][bw + (NH) * 32][0]);                          \
    gload_lds16(bsrc + (size_t)(128 + (NH) * 32) * 768 + (KT) * 64,            \
                &TILES[(BUF)][1][128 + bw + (NH) * 32][0]);                    \
  } while (0)

#define LOAD_A(BUF, MH)                                                        \
  do {                                                                         \
    const char* _p =                                                           \
        (const char*)&TILES[(BUF)][0][wm2 * 128 + (MH) * 64 + l15][0];         \
    af[0][0] = *(const bf16x8*)(_p + ca0);                                     \
    af[0][1] = *(const bf16x8*)(_p + ca1);                                     \
    af[1][0] = *(const bf16x8*)(_p + 2048 + ca0);                              \
    af[1][1] = *(const bf16x8*)(_p + 2048 + ca1);                              \
    af[2][0] = *(const bf16x8*)(_p + 4096 + ca0);                              \
    af[2][1] = *(const bf16x8*)(_p + 4096 + ca1);                              \
    af[3][0] = *(const bf16x8*)(_p + 6144 + ca0);                              \
    af[3][1] = *(const bf16x8*)(_p + 6144 + ca1);                              \
  } while (0)

#define LOAD_B(BUF, NH)                                                        \
  do {                                                                         \
    const char* _p =                                                           \
        (const char*)&TILES[(BUF)][1][wn * 64 + (NH) * 32 + l15][0];           \
    bfr[0][0] = *(const bf16x8*)(_p + ca0);                                    \
    bfr[0][1] = *(const bf16x8*)(_p + ca1);                                    \
    bfr[1][0] = *(const bf16x8*)(_p + 2048 + ca0);                             \
    bfr[1][1] = *(const bf16x8*)(_p + 2048 + ca1);                             \
  } while (0)

#define MFMA_Q(MH, NH)                                                         \
  do {                                                                         \
    _Pragma("unroll") for (int _i = 0; _i < 4; ++_i)                           \
        _Pragma("unroll") for (int _j = 0; _j < 2; ++_j)                       \
            acc[(MH) * 4 + _i][(NH) * 2 + _j] =                                \
        __builtin_amdgcn_mfma_f32_16x16x32_bf16(                               \
            af[_i][0], bfr[_j][0], acc[(MH) * 4 + _i][(NH) * 2 + _j], 0, 0,    \
            0);                                                                \
    _Pragma("unroll") for (int _i = 0; _i < 4; ++_i)                           \
        _Pragma("unroll") for (int _j = 0; _j < 2; ++_j)                       \
            acc[(MH) * 4 + _i][(NH) * 2 + _j] =                                \
        __builtin_amdgcn_mfma_f32_16x16x32_bf16(                               \
            af[_i][1], bfr[_j][1], acc[(MH) * 4 + _i][(NH) * 2 + _j], 0, 0,    \
            0);                                                                \
  } while (0)

#define PH_MID                                                                 \
  do {                                                                         \
    asm volatile("" ::: "memory");                                             \
    __builtin_amdgcn_s_barrier();                                              \
    asm volatile("s_waitcnt lgkmcnt(0)" ::: "memory");                         \
    __builtin_amdgcn_s_setprio(1);                                             \
  } while (0)

#define PH_END                                                                 \
  do {                                                                         \
    __builtin_amdgcn_s_setprio(0);                                             \
    asm volatile("" ::: "memory");                                             \
    __builtin_amdgcn_s_barrier();                                              \
    asm volatile("" ::: "memory");                                             \
  } while (0)

__global__ __launch_bounds__(512, 2) void qkv_gemm(
    const u16* __restrict__ Xb,   // [9232][768] bf16
    const u16* __restrict__ WT,   // [3][768][768] n-major bf16
    const float* __restrict__ bq, const float* __restrict__ bv,
    u16* __restrict__ qkv) {
  const int bid = blockIdx.x;
  const int xcd = bid & 7;
  const int r8 = bid >> 3;                 // 0..44
  const int mt = (r8 / 9) * 8 + xcd;       // all 9 nt of one mt -> same XCD
  if (mt >= 37) return;
  const int nt = r8 % 9;
  const int m0 = mt * 256;
  const int widx = nt / 3;                 // 0=q, 1=k, 2=v
  const int nb = (nt % 3) * 256;           // col base within [0,768)

  const int tid = threadIdx.x;
  const int lane = tid & 63;
  const int w = tid >> 6;                  // 0..7
  const int wm2 = w >> 2;                  // 0..1 (M half)
  const int wn = w & 3;                    // 0..3 (N quarter)
  const int quad = lane >> 4;
  const int l15 = lane & 15;

  __shared__ u16 TILES[2][2][256][64];     // 128 KiB

  // ---- staging addressing (per-lane swizzled global src, per-wave LDS base)
  const int lr = lane >> 3;                // row within an 8-row group
  const int w8 = w * 8;
  const int ce = ((lane & 7) ^ lr) * 8;    // swizzled src element offset
  const u16* asrc[4];                      // A chunk row bases 0/64/128/192
#pragma unroll
  for (int c = 0; c < 4; ++c) {
    int rr = m0 + c * 64 + w8 + lr;
    if (rr > MTOT - 1) rr = MTOT - 1;      // clamped rows: garbage, not stored
    asrc[c] = Xb + (size_t)rr * 768 + ce;
  }
  const int bw = (w >> 2) * 64 + (w & 3) * 8;
  const u16* bsrc = WT + (size_t)widx * 589824 + (size_t)(nb + bw + lr) * 768 + ce;

  // ---- ds_read addressing (swizzled) ----
  const int lswz = (l15 & 7) << 4;
  const int ca0 = (quad * 16) ^ lswz;      // k-half 0
  const int ca1 = ca0 ^ 64;                // k-half 1

  f32x4 acc[8][4];
#pragma unroll
  for (int i = 0; i < 8; ++i)
#pragma unroll
    for (int j = 0; j < 4; ++j) acc[i][j] = (f32x4){0.f, 0.f, 0.f, 0.f};
  bf16x8 af[4][2], bfr[2][2];

  // ---- prologue: half-tiles 0..6 (tile0 full + tile1 q0,q1,q2) ----
  STAGE_A(0, 0, 0); STAGE_B(0, 0, 1); STAGE_A(0, 0, 1); STAGE_B(0, 0, 0);
  STAGE_A(1, 1, 0); STAGE_B(1, 1, 1); STAGE_A(1, 1, 1);
  asm volatile("s_waitcnt vmcnt(6)" ::: "memory");  // tile0 landed; 3 in flight
  __builtin_amdgcn_s_barrier();
  asm volatile("" ::: "memory");

  // ---- main loop: 12 K-tiles x 4 phases; stage stream s = phase+7 ----
  for (int t = 0; t < 12; ++t) {
    const int buf = t & 1;
    const int nbuf = buf ^ 1;
    // P0 (mh0,nh0): 12 ds_reads; stage B-nh0 of tile t+1 (other buf)
    LOAD_A(buf, 0);
    LOAD_B(buf, 0);
    if (t <= 10) STAGE_B(nbuf, t + 1, 0);
    PH_MID; MFMA_Q(0, 0); PH_END;
    // P1 (mh0,nh1): 4 ds_reads; stage A-mh0 of t+2 (cur buf; freed after P0)
    LOAD_B(buf, 1);
    if (t <= 9) STAGE_A(buf, t + 2, 0);
    PH_MID; MFMA_Q(0, 1); PH_END;
    // P2 (mh1,nh1): 8 ds_reads; stage B-nh1 of t+2 (cur buf; freed after P1)
    LOAD_A(buf, 1);
    if (t <= 9) STAGE_B(buf, t + 2, 1);
    PH_MID; MFMA_Q(1, 1); PH_END;
    // P3 (mh1,nh0): 4 ds_reads; stage A-mh1 of t+2 (cur buf; freed after P2)
    LOAD_B(buf, 0);
    if (t <= 9) STAGE_A(buf, t + 2, 1);
    asm volatile("" ::: "memory");
    __builtin_amdgcn_s_barrier();
    asm volatile("s_waitcnt lgkmcnt(0)" ::: "memory");
    __builtin_amdgcn_s_setprio(1);
    MFMA_Q(1, 0);
    __builtin_amdgcn_s_setprio(0);
    // K-tile boundary: counted wait -- next tile landed, 3 half-tiles in flight
    if (t < 10) {
      asm volatile("s_waitcnt vmcnt(6)" ::: "memory");
    } else if (t == 10) {
      asm volatile("s_waitcnt vmcnt(0)" ::: "memory");
    }
    asm volatile("" ::: "memory");
    __builtin_amdgcn_s_barrier();
    asm volatile("" ::: "memory");
  }

  // ---- epilogue: scale+bias (QSCALE folds 0.125*log2e), LDS-staged stores ----
  const float scale = (widx == 0) ? QSCALE : 1.0f;
  float biasv[4];
#pragma unroll
  for (int nf = 0; nf < 4; ++nf) {
    int n = nb + wn * 64 + nf * 16 + l15;
    biasv[nf] = (widx == 0) ? bq[n] * QSCALE : (widx == 2) ? bv[n] : 0.f;
  }
  u16* E = (u16*)TILES;                    // 256 x 256 u16 (reuses all 128 KiB)
#pragma unroll
  for (int mf = 0; mf < 8; ++mf)
#pragma unroll
    for (int nf = 0; nf < 4; ++nf)
#pragma unroll
      for (int rr = 0; rr < 4; ++rr) {
        int rowl = wm2 * 128 + mf * 16 + quad * 4 + rr;
        int col = wn * 64 + nf * 16 + l15;
        E[rowl * 256 + (col ^ (quad << 4))] =
            f2bf(acc[mf][nf][rr] * scale + biasv[nf]);
      }
  __syncthreads();
  u16* ob = qkv + (size_t)widx * QKV_STRIDE + nb;
#pragma unroll 4
  for (int pass = 0; pass < 16; ++pass) {
    int c = pass * 512 + tid;
    int row = c >> 5, ch = c & 31;
    int m = m0 + row;
    if (m < MTOT) {
      int colr = (ch * 8) ^ (((row >> 2) & 3) << 4);
      *(int4*)(ob + (size_t)m * 768 + ch * 8) = *(const int4*)&E[row * 256 + colr];
    }
  }
}

// ---------------- flash attention (no-max softmax), 512 threads / 128 q-rows ----------------
// grid (bh=192, qt=5): 192%8==0 pins all qt-blocks of one (b,h) to one XCD.
// R15: l = P x ones MFMA. R20: __builtin_amdgcn_exp2f. R21: biasT short4
// loads (4x 8B per lane per tile; in-loop, no prefetch state -> VGPR stays
// under the 64 / 8-waves-per-SIMD ceiling). Last tile (kbase=576) selects
// -144 for keys > 576 (uniform branch; pad keys' P flushes to 0).
__global__ __launch_bounds__(512) void attn(
    const u16* __restrict__ qk, const u16* __restrict__ vT,
    const u16* __restrict__ biasT, float* __restrict__ out) {
  const int bh = blockIdx.x;  // b*12+h
  const int qt = blockIdx.y;  // 0..4
  const int b = bh / 12, h = bh - b * 12;
  const int tid = threadIdx.x;
  const int lane = tid & 63;
  const int w = tid >> 6;     // 0..7
  const int quad = lane >> 4;
  const int l15 = lane & 15;

  const u16* qp = qk + (size_t)b * SEQ * 768 + h * 64;  // row stride 768
  const u16* kp = qp + (size_t)QKV_STRIDE;
  const u16* vtp = vT + (size_t)bh * 64 * VT_PITCH;
  const u16* btp = biasT + (size_t)h * BT_K * BT_Q;

  __shared__ u16 Ks[64][72];     // [key][d]
  __shared__ u16 VTs[64][72];    // [d][key]
  __shared__ u16 Ps[8][16][72];  // per-wave P tile, XOR-swizzled chunks

  const int qrow0 = qt * 128 + w * 16;

  bf16x8 qf[2];
  {
    int row = qrow0 + l15;
    if (row > 576) row = 576;  // clamp; clamped rows never stored
    qf[0] = *(const bf16x8*)(qp + (size_t)row * 768 + quad * 8);
    qf[1] = *(const bf16x8*)(qp + (size_t)row * 768 + 32 + quad * 8);
  }
  // bias qrow base (4 consecutive rows, 8B-aligned). Clamp to 576: real row
  // 576 keeps its exact bias (.x component); rows 577..579 are dead.
  int qb = qrow0 + quad * 4;
  if (qb > 576) qb = 576;

  const short one_bf = (short)0x3F80;      // bf16 1.0
  const bf16x8 vones = {one_bf, one_bf, one_bf, one_bf,
                        one_bf, one_bf, one_bf, one_bf};

  f32x4 Ol = (f32x4){0.f, 0.f, 0.f, 0.f};  // row sums l (per quad-row)
  f32x4 O[4];
#pragma unroll
  for (int dt = 0; dt < 4; ++dt) O[dt] = (f32x4){0.f, 0.f, 0.f, 0.f};

  for (int kt = 0; kt < 10; ++kt) {
    const int kbase = kt * 64;
    const bool full = (kbase + 64 <= SEQ);   // tiles 0..8: all keys real
    // bias loads first (independent VMEM, latency overlaps staging)
    short4 pb[4];
#pragma unroll
    for (int nt = 0; nt < 4; ++nt) {
      int kb = kbase + nt * 16 + l15;
      int kc = kb > 576 ? 576 : kb;          // no-op for tiles 0..8
      pb[nt] = *(const short4*)(btp + (size_t)kc * BT_Q + qb);
    }

    // stage K [key][d] and V^T window [d][key] — 512 threads = one pass each
    {
      int rr = tid >> 3, ko = (tid & 7) << 3;
      int gk = kbase + rr;
      int4 kvv = make_int4(0, 0, 0, 0);
      if (gk < SEQ) kvv = *(const int4*)(kp + (size_t)gk * 768 + ko);
      *(int4*)&Ks[rr][ko] = kvv;
      *(int4*)&VTs[rr][ko] = *(const int4*)(vtp + (size_t)rr * VT_PITCH + kbase + ko);
    }
    __syncthreads();

    // S = Q K^T + bias  (bias as MFMA C-init; q pre-scaled by 0.125*log2e,
    // bias pre-scaled by log2e; pad keys (last tile): bias=-144 -> 2^s = 0)
    f32x4 s[4];
#pragma unroll
    for (int nt = 0; nt < 4; ++nt) {
      f32x4 z;
      if (full) {
        z = (f32x4){bf2f((u16)pb[nt].x), bf2f((u16)pb[nt].y),
                    bf2f((u16)pb[nt].z), bf2f((u16)pb[nt].w)};
      } else {
        bool v = (kbase + nt * 16 + l15) <= 576;
        z = (f32x4){v ? bf2f((u16)pb[nt].x) : -144.f,
                    v ? bf2f((u16)pb[nt].y) : -144.f,
                    v ? bf2f((u16)pb[nt].z) : -144.f,
                    v ? bf2f((u16)pb[nt].w) : -144.f};
      }
      bf16x8 kf0 = *(const bf16x8*)(&Ks[nt * 16 + l15][quad * 8]);
      bf16x8 kf1 = *(const bf16x8*)(&Ks[nt * 16 + l15][32 + quad * 8]);
      z = __builtin_amdgcn_mfma_f32_16x16x32_bf16(qf[0], kf0, z, 0, 0, 0);
      z = __builtin_amdgcn_mfma_f32_16x16x32_bf16(qf[1], kf1, z, 0, 0, 0);
      s[nt] = z;
    }

    // p = 2^s via raw v_exp_f32 (builtin); truncate to bf16 into Ps
#pragma unroll
    for (int nt = 0; nt < 4; ++nt) {
#pragma unroll
      for (int r = 0; r < 4; ++r) {
        float p = __builtin_amdgcn_exp2f(s[nt][r]);
        unsigned int u = __float_as_uint(p);
        Ps[w][quad * 4 + r][((nt ^ quad) << 4) + l15] = (u16)(u >> 16);
      }
    }

    // O += P V; Ol += P x ones (row-sum on the matrix pipe)
#pragma unroll
    for (int ks = 0; ks < 2; ++ks) {
      int cc = (ks * 32 + quad * 8) ^ ((l15 >> 2) << 4);
      bf16x8 pf = *(const bf16x8*)(&Ps[w][l15][cc]);
#pragma unroll
      for (int dt = 0; dt < 4; ++dt) {
        bf16x8 vf = *(const bf16x8*)(&VTs[dt * 16 + l15][ks * 32 + quad * 8]);
        O[dt] = __builtin_amdgcn_mfma_f32_16x16x32_bf16(pf, vf, O[dt], 0, 0, 0);
      }
      Ol = __builtin_amdgcn_mfma_f32_16x16x32_bf16(pf, vones, Ol, 0, 0, 0);
    }
    __syncthreads();  // protect Ks/VTs/Ps before next tile's staging
  }

  // epilogue: l available per-lane from the ones-MFMA (no reduction needed)
#pragma unroll
  for (int r = 0; r < 4; ++r) {
    int row = qrow0 + quad * 4 + r;
    if (row < SEQ) {
      float inv = 1.f / Ol[r];
#pragma unroll
      for (int dt = 0; dt < 4; ++dt)
        out[((size_t)(b * SEQ + row)) * 768 + h * 64 + dt * 16 + l15] = O[dt][r] * inv;
    }
  }
}

extern "C" void kernel_launch(void* const* d_in, const int* in_sizes, int n_in,
                              void* d_out, int out_size, void* d_ws, size_t ws_size,
                              hipStream_t stream) {
  const float* hs = (const float*)d_in[0];
  const float* Wq = (const float*)d_in[1];
  const float* bq = (const float*)d_in[2];
  const float* Wk = (const float*)d_in[3];
  const float* Wv = (const float*)d_in[4];
  const float* bv = (const float*)d_in[5];
  const float* table = (const float*)d_in[6];
  const int* idx = (const int*)d_in[7];
  float* out = (float*)d_out;

  char* ws = (char*)d_ws;
  u16* qkv = (u16*)ws;                          // [0, 42541056)
  u16* WT = (u16*)(ws + 42541056);              // phase 1
  u16* Xb = (u16*)(ws + 46080000);              // phase 1
  u16* vT = (u16*)(ws + 42541056);              // phase 2 (over WT + Xb head)
  u16* biasT = (u16*)(ws + 58269696);           // phase 2 (over Xb tail)

  // phase 1: prep (transpose_w + cvt_x) -> GEMM
  hipLaunchKernelGGL(prep, dim3(5190), dim3(256), 0, stream, Wq, Wk, Wv, hs, WT, Xb);
  hipLaunchKernelGGL(qkv_gemm, dim3(360), dim3(512), 0, stream, Xb, WT, bq, bv, qkv);
  // phase 2: prep2 (transpose_v + biasT gather) -> attention
  hipLaunchKernelGGL(prep2, dim3(1537), dim3(256), 0, stream,
                     qkv + 2 * (size_t)QKV_STRIDE, vT, table, idx, biasT);
  hipLaunchKernelGGL(attn, dim3(192, 5), dim3(512), 0, stream, qkv, vT, biasT, out);
}